// Round 12
// baseline (592.223 us; speedup 1.0000x reference)
//
#include <hip/hip_runtime.h>
#include <hip/hip_bf16.h>
#include <type_traits>

typedef __hip_bfloat16 bf16;
typedef __attribute__((ext_vector_type(8))) short s16x8;
typedef __attribute__((ext_vector_type(4))) short s16x4;
typedef __attribute__((ext_vector_type(4))) float f32x4;

#define DEVI __device__ __forceinline__

DEVI float bf2f(bf16 x) { return __bfloat162float(x); }
DEVI float to_f(float x) { return x; }
DEVI float to_f(bf16 x) { return __bfloat162float(x); }
// erf via Abramowitz-Stegun 7.1.26 (|err| <= 1.5e-7), branchless.
DEVI float gelu_f(float x) {
  const float y = x * 0.7071067811865476f;
  const float a = fabsf(y);
  const float t = __builtin_amdgcn_rcpf(1.0f + 0.3275911f * a);
  const float p = t * (0.254829592f + t * (-0.284496736f +
                  t * (1.421413741f + t * (-1.453152027f + t * 1.061405429f))));
  const float e = __expf(-a * a);
  const float erfv = copysignf(1.0f - p * e, y);
  return 0.5f * x * (1.0f + erfv);
}
DEVI float elu1(float x) { return x > 0.f ? x + 1.f : __expf(x); }  // elu(x)+1
DEVI float s2f(short s) {
  unsigned u = ((unsigned)(unsigned short)s) << 16;
  float f; __builtin_memcpy(&f, &u, 4); return f;
}
DEVI short f2s(float x) {
  bf16 h = __float2bfloat16(x);
  short s; __builtin_memcpy(&s, &h, 2); return s;
}

// ---------------- dtype detector (fallback when host can't tell) ----------
__global__ void detect_kernel(const void* x0, int* dflag) {
  const int t = threadIdx.x;                  // 64 threads
  const bf16* p = (const bf16*)x0;
  float v = bf2f(p[t * 2]);
  bool ok = (fabsf(v) <= 64.0f);              // false for NaN too
  unsigned long long m = __ballot(ok);
  if (t == 0) dflag[0] = (m == ~0ull) ? 0 : 1;   // 0 = bf16, 1 = fp32
}

// ---------------- bn scale/shift + merge-bias precompute ----------------
// layout: s0[256] t0[256] s1[1024] t1[1024] s2[1024] t2[1024] s3[256] t3[256] mbias[256]
template <typename TIN>
__global__ __launch_bounds__(256) void bnprep_kernel(
    const int* dflag, int want,
    const TIN* g0, const TIN* b0, const TIN* m0, const TIN* v0,
    const TIN* g1, const TIN* b1, const TIN* m1, const TIN* v1,
    const TIN* g2, const TIN* b2, const TIN* m2, const TIN* v2,
    const TIN* g3, const TIN* b3, const TIN* m3, const TIN* v3,
    const TIN* mb, float* out)
{
  if (want >= 0 && dflag[0] != want) return;
  int t = threadIdx.x;
  {
    float s = to_f(g0[t]) / sqrtf(to_f(v0[t]) + 1e-5f);
    out[t] = s; out[256 + t] = to_f(b0[t]) - to_f(m0[t]) * s;
  }
  for (int i = t; i < 1024; i += 256) {
    float s = to_f(g1[i]) / sqrtf(to_f(v1[i]) + 1e-5f);
    out[512 + i] = s; out[1536 + i] = to_f(b1[i]) - to_f(m1[i]) * s;
  }
  for (int i = t; i < 1024; i += 256) {
    float s = to_f(g2[i]) / sqrtf(to_f(v2[i]) + 1e-5f);
    out[2560 + i] = s; out[3584 + i] = to_f(b2[i]) - to_f(m2[i]) * s;
  }
  {
    float s = to_f(g3[t]) / sqrtf(to_f(v3[t]) + 1e-5f);
    out[4608 + t] = s; out[4864 + t] = to_f(b3[t]) - to_f(m3[t]) * s;
    out[5120 + t] = to_f(mb[t]);
  }
}

// ---------------- weight convert to bf16 (concatenated dst) ----------------
template <typename TIN>
__global__ __launch_bounds__(256) void wconv_kernel(
    const int* dflag, int want,
    const TIN* qw, const TIN* kw, const TIN* vw, const TIN* mw,
    const TIN* w1, const TIN* w2, const TIN* dw, bf16* dst)
{
  if (want >= 0 && dflag[0] != want) return;
  int i = blockIdx.x * 256 + threadIdx.x;
  if (i >= 795648) return;
  const TIN* src; int off;
  if (i < 262144) {
    src = (i < 65536) ? qw : (i < 131072) ? kw : (i < 196608) ? vw : mw;
    off = i & 65535;
  } else if (i < 524288) { src = w1; off = i - 262144; }
  else if (i < 786432) { src = w2; off = i - 524288; }
  else {
    src = dw;
    const int o = i - 786432;           // o = tap*1024 + m
    const int tap = o >> 10, m = o & 1023;
    off = m * 9 + tap;                  // src is [m][tap]
    if (o >= 9216) return;
  }
  dst[i] = __float2bfloat16(to_f(src[off]));
}

// ---------------- prenorm + transpose via LDS tiles (gelu only) -------------
// Also emits per-(window,row) partial sums of gelu(bn0 x) into xmp
// [b][wrow][ch][win] (unique slot per thread/cc -> plain stores, no atomics).
template <typename TIN>
__global__ __launch_bounds__(256) void prenorm_t_kernel(
    const int* dflag, int want, const TIN* __restrict__ x0,
    const float* __restrict__ bn, bf16* __restrict__ xhat_t,
    float* __restrict__ xmp)
{
  if (want >= 0 && dflag[0] != want) return;
  __shared__ float T[128][67];
  const int t = threadIdx.x;
  const int tile = blockIdx.x;          // 512 tiles of 64 px
  const int b = tile >> 8;              // 256 tiles per batch
  const int rc = tile & 255;
  const int p0 = rc * 64;               // pixel base within batch
  const int row = rc >> 1, colh = rc & 1;
  const int win = (row >> 3) * 16 + colh * 8 + (t & 7);
  const int wrow = row & 7;
  const long xbase = (long)b * 4194304 + p0;
  const int px_off = (t & 7) * 8;
  const int chr = t >> 3;               // 0..31
  const int ch8 = (t & 15) * 8;
  const int pxw = t >> 4;               // 0..15
  #pragma unroll
  for (int pass = 0; pass < 2; ++pass) {
    const int Hc = pass * 128;
    __syncthreads();                    // prev pass's LDS reads done
    #pragma unroll
    for (int cc = 0; cc < 4; ++cc) {
      const int ch = Hc + chr + 32 * cc;
      const TIN* xp = x0 + (long)ch * 16384 + xbase + px_off;
      float v[8];
      if constexpr (sizeof(TIN) == 2) {
        const s16x8 r = *(const s16x8*)xp;
        #pragma unroll
        for (int j = 0; j < 8; ++j) v[j] = s2f(r[j]);
      } else {
        const float4 a = *(const float4*)xp;
        const float4 c = *(const float4*)(xp + 4);
        v[0] = a.x; v[1] = a.y; v[2] = a.z; v[3] = a.w;
        v[4] = c.x; v[5] = c.y; v[6] = c.z; v[7] = c.w;
      }
      const float s0 = bn[ch], t0 = bn[256 + ch];
      #pragma unroll
      for (int j = 0; j < 8; ++j) v[j] = gelu_f(v[j] * s0 + t0);
      float s8 = v[0];
      #pragma unroll
      for (int j = 1; j < 8; ++j) s8 += v[j];
      xmp[(((b * 8 + wrow) * 256 + ch) << 8) + win] = s8;
      float* Tr = &T[chr + 32 * cc][px_off];
      #pragma unroll
      for (int j = 0; j < 8; ++j) Tr[j] = v[j];
    }
    __syncthreads();
    #pragma unroll
    for (int it = 0; it < 4; ++it) {
      const int px = pxw + 16 * it;
      alignas(16) short o[8];
      #pragma unroll
      for (int j = 0; j < 8; ++j) o[j] = f2s(T[ch8 + j][px]);
      *(uint4*)(xhat_t + (long)(b * 16384 + p0 + px) * 256 + Hc + ch8) =
          *(const uint4*)o;
    }
  }
}

// ---------------- reduce xmp partials -> window means xm [b][c][nw] ---------
__global__ __launch_bounds__(256) void xred_kernel(const float* __restrict__ xmp,
                                                   float* __restrict__ xm)
{
  const int tid = blockIdx.x * 256 + threadIdx.x;   // < 131072
  const int nw = tid & 255, c = (tid >> 8) & 255, b = tid >> 16;
  float s = 0.f;
  #pragma unroll
  for (int w = 0; w < 8; ++w)
    s += xmp[(((b * 8 + w) * 256 + c) << 8) + nw];
  xm[tid] = s * 0.015625f;
}

// ---------------- MFMA GEMM: out[n][m] = epi( sum_k in[n][k] * w[m][k] ) ----
// K-step 64 (T3 2-phase): per step, stage [128][64] A and B tiles (each
// thread 4 uint4 per matrix), issue next step's loads before the two 32-k
// MFMA sub-steps -> HALF the barriers per MFMA vs K-step 32; HBM latency
// still hides under compute. Accumulation order unchanged (ascending k).
// MODE 0 PLAIN : out bf16 = elu1(acc) when m0<512 (Q/K pre-activation)
// MODE 1 MERGE : out bf16 = acc + sv[m] + x0[b][m][pix] (LDS-staged residual)
// MODE 2 W1    : out bf16 = gelu(acc*sv[m]+tv[m])
// MODE 3 OUT   : channel-major via LDS transpose; batch-aware; isfp dtype
// MODE 4 KVT   : window-gathered N-tiles -> fragment-major kvT + fused wsum
template <int MODE, typename TRES = bf16>
__global__ __launch_bounds__(256) void mfma_gemm(
    const int* dflag, int want, int isfp,
    const bf16* __restrict__ in, const bf16* __restrict__ w,
    void* __restrict__ out, long obase, const void* __restrict__ resv,
    const float* __restrict__ sv, const float* __restrict__ tv,
    float* __restrict__ aux, int N, int M, int K)
{
  if (want >= 0 && dflag[0] != want) return;
  alignas(16) __shared__ char smem[36864];   // staging [128][72]x2; epi tiles fit
  bf16* inT = (bf16*)smem;                   // [128][72]
  bf16* wT  = (bf16*)(smem + 18432);         // [128][72]
  const int t = threadIdx.x;
  const int n0 = blockIdx.x * 128, m0 = blockIdx.y * 128;
  const int sr = t >> 1, kof = (t & 1) * 32;
  const int wid = t >> 6, lane = t & 63;
  const int nw = (wid & 1) * 64, mw = (wid >> 1) * 64;
  const int l15 = lane & 15, quad = lane >> 4;
  f32x4 acc[4][4];
  #pragma unroll
  for (int i = 0; i < 4; ++i)
    #pragma unroll
    for (int j = 0; j < 4; ++j) acc[i][j] = 0.f;
  long inRowB;
  if (MODE == 4) {
    // gathered A row: tile-local sr -> pixel of window (w0 + sr>>6)
    const int bb4 = n0 >> 14, w0 = (n0 & 16383) >> 6;
    const int win = w0 + (sr >> 6);
    const int rr = (sr >> 3) & 7, cc = sr & 7;
    inRowB = ((long)(bb4 * 16384 + ((win >> 4) * 8 + rr) * 128
                    + (win & 15) * 8 + cc)) * K;
  } else {
    inRowB = (long)(n0 + sr) * K;
  }
  const long wRowB = (long)(m0 + sr) * K;
  // prologue: K-tile 0 in flight (4 uint4 per matrix per thread)
  uint4 a[4], b[4];
  #pragma unroll
  for (int q = 0; q < 4; ++q) {
    a[q] = *(const uint4*)(in + inRowB + kof + q * 8);
    b[q] = *(const uint4*)(w + wRowB + kof + q * 8);
  }
  for (int k0 = 0; k0 < K; k0 += 64) {
    __syncthreads();                         // prev iter's ds_reads done
    #pragma unroll
    for (int q = 0; q < 4; ++q) {
      *(uint4*)(inT + sr * 72 + kof + q * 8) = a[q];
      *(uint4*)(wT + sr * 72 + kof + q * 8) = b[q];
    }
    __syncthreads();
    if (k0 + 64 < K) {                       // issue NEXT K-tile before MFMA
      #pragma unroll
      for (int q = 0; q < 4; ++q) {
        a[q] = *(const uint4*)(in + inRowB + k0 + 64 + kof + q * 8);
        b[q] = *(const uint4*)(w + wRowB + k0 + 64 + kof + q * 8);
      }
    }
    #pragma unroll
    for (int sub = 0; sub < 2; ++sub) {
      s16x8 af[4], bfv[4];
      #pragma unroll
      for (int i = 0; i < 4; ++i)
        af[i] = *(const s16x8*)(inT + (nw + i * 16 + l15) * 72 + sub * 32 + quad * 8);
      #pragma unroll
      for (int i = 0; i < 4; ++i)
        bfv[i] = *(const s16x8*)(wT + (mw + i * 16 + l15) * 72 + sub * 32 + quad * 8);
      #pragma unroll
      for (int i = 0; i < 4; ++i)
        #pragma unroll
        for (int j = 0; j < 4; ++j)
          acc[i][j] = __builtin_amdgcn_mfma_f32_16x16x32_bf16(af[i], bfv[j], acc[i][j], 0, 0, 0);
    }
  }
  if (MODE == 0 || MODE == 2) {
    bf16* ob = (bf16*)out;
    const bool doelu = (MODE == 0) && (m0 < 512);   // Q,K rows pre-activated
    #pragma unroll
    for (int i = 0; i < 4; ++i) {
      #pragma unroll
      for (int r = 0; r < 4; ++r) {
        const int n = n0 + nw + i * 16 + quad * 4 + r;
        #pragma unroll
        for (int j = 0; j < 4; ++j) {
          const int m = m0 + mw + j * 16 + l15;
          float vv = acc[i][j][r];
          if (MODE == 0) { if (doelu) vv = elu1(vv); }
          if (MODE == 2) vv = gelu_f(vv * sv[m] + tv[m]);
          ob[(long)n * M + m] = __float2bfloat16(vv);
        }
      }
    }
  } else if (MODE == 1) {
    // stage x0 residual tile [128 ch][128 px] through LDS (bf16)
    __syncthreads();                         // staging LDS dead
    bf16* xL = (bf16*)smem;                  // [128][132]
    {
      const int bb = n0 >> 14, nloc = n0 & 16383;
      const int chl = t >> 1, pxh = (t & 1) * 64;
      const TRES* xp = (const TRES*)resv + (long)bb * 4194304
                     + (long)(m0 + chl) * 16384 + nloc + pxh;
      alignas(16) short tmp[64];
      if constexpr (std::is_same<TRES, float>::value) {
        #pragma unroll
        for (int q = 0; q < 16; ++q) {
          const float4 f = *(const float4*)(xp + q * 4);
          tmp[q * 4 + 0] = f2s(f.x); tmp[q * 4 + 1] = f2s(f.y);
          tmp[q * 4 + 2] = f2s(f.z); tmp[q * 4 + 3] = f2s(f.w);
        }
      } else {
        #pragma unroll
        for (int q = 0; q < 8; ++q)
          *(s16x8*)(tmp + q * 8) = *(const s16x8*)((const bf16*)xp + q * 8);
      }
      bf16* xd = xL + chl * 132 + pxh;
      #pragma unroll
      for (int q = 0; q < 8; ++q)
        *(uint4*)(xd + q * 8) = *(const uint4*)(tmp + q * 8);
    }
    __syncthreads();
    bf16* ob = (bf16*)out;
    #pragma unroll
    for (int i = 0; i < 4; ++i)
      #pragma unroll
      for (int r = 0; r < 4; ++r) {
        const int nl = nw + i * 16 + quad * 4 + r;
        const int n = n0 + nl;
        #pragma unroll
        for (int j = 0; j < 4; ++j) {
          const int ml = mw + j * 16 + l15;
          const int m = m0 + ml;
          const float vv = acc[i][j][r] + sv[m] + bf2f(xL[ml * 132 + nl]);
          ob[(long)n * 256 + m] = __float2bfloat16(vv);
        }
      }
  } else {
    const int isf = (MODE == 3) ? (isfp >= 0 ? isfp : dflag[0]) : 0;
    __syncthreads();                         // staging LDS now dead
    bf16* T = (bf16*)smem;                   // [128][136]
    #pragma unroll
    for (int i = 0; i < 4; ++i)
      #pragma unroll
      for (int r = 0; r < 4; ++r) {
        const int n = nw + i * 16 + quad * 4 + r;
        #pragma unroll
        for (int j = 0; j < 4; ++j) {
          const int m = mw + j * 16 + l15;
          float vv = acc[i][j][r];
          if (MODE == 3)
            vv = vv * sv[m0 + m] + tv[m0 + m]
               + bf2f(((const bf16*)resv)[(long)(n0 + n) * 256 + m0 + m]);
          else { if (m0 + m < 256) vv = elu1(vv); }
          T[m * 136 + n] = __float2bfloat16(vv);
        }
      }
    __syncthreads();
    const int mr = t >> 1, half = (t & 1) * 64;
    if (MODE == 4) {
      const int bb4 = n0 >> 14, w0 = (n0 & 16383) >> 6;
      const int gm = m0 + mr;
      bf16* bo = (bf16*)out;
      #pragma unroll
      for (int jj = 0; jj < 8; ++jj) {
        const int C = half + jj * 8;
        const int win = w0 + (C >> 6);
        const int pxc = (C & 63) >> 3;
        *(uint4*)(bo + ((long)(bb4 * 256 + win) << 15) + pxc * 4096 + gm * 8) =
            *(const uint4*)(T + mr * 136 + C);
      }
      if (m0 < 256) {                        // fused wsum
        float s = 0.f;
        const bf16* Tr = T + mr * 136 + half;
        #pragma unroll
        for (int c8 = 0; c8 < 8; ++c8) {
          const s16x8 v = *(const s16x8*)(Tr + c8 * 8);
          #pragma unroll
          for (int e = 0; e < 8; ++e) s += s2f(v[e]);
        }
        aux[(long)(bb4 * 256 + w0 + (half >> 6)) * 256 + gm] = s;
      }
    } else {
      // MODE 3: batch-aware channel-major output
      const int bb3 = n0 >> 14, nloc = n0 & 16383;
      if (!isf) {
        bf16* bo = (bf16*)out + obase + (long)bb3 * 4194304;
        #pragma unroll
        for (int jj = 0; jj < 8; ++jj)
          *(uint4*)(bo + (long)(m0 + mr) * 16384 + nloc + half + jj * 8) =
              *(const uint4*)(T + mr * 136 + half + jj * 8);
      } else {
        float* fo = (float*)out + obase + (long)bb3 * 4194304;
        #pragma unroll
        for (int jj = 0; jj < 8; ++jj)
          #pragma unroll
          for (int e = 0; e < 8; ++e)
            fo[(long)(m0 + mr) * 16384 + nloc + half + jj * 8 + e] =
                bf2f(T[mr * 136 + half + jj * 8 + e]);
      }
    }
  }
}

// ---------------- project window means through q_w/k_w (fp32, 4-way ILP) ----
template <typename TIN>
__global__ __launch_bounds__(256) void meanproj_kernel(const int* dflag, int want,
    const TIN* __restrict__ qw, const TIN* __restrict__ kw,
    const float* __restrict__ xm, float* __restrict__ qm, float* __restrict__ km)
{
  if (want >= 0 && dflag[0] != want) return;
  int tid = blockIdx.x * 256 + threadIdx.x;      // < 131072
  int nw = tid & 255, o = (tid >> 8) & 255, b = tid >> 16;
  float q0 = 0.f, q1 = 0.f, q2 = 0.f, q3 = 0.f;
  float k0 = 0.f, k1 = 0.f, k2 = 0.f, k3 = 0.f;
  for (int c = 0; c < 256; c += 4) {
    const float x0v = xm[((b * 256 + c) << 8) + nw];
    const float x1v = xm[((b * 256 + c + 1) << 8) + nw];
    const float x2v = xm[((b * 256 + c + 2) << 8) + nw];
    const float x3v = xm[((b * 256 + c + 3) << 8) + nw];
    q0 += to_f(qw[o * 256 + c]) * x0v;     k0 += to_f(kw[o * 256 + c]) * x0v;
    q1 += to_f(qw[o * 256 + c + 1]) * x1v; k1 += to_f(kw[o * 256 + c + 1]) * x1v;
    q2 += to_f(qw[o * 256 + c + 2]) * x2v; k2 += to_f(kw[o * 256 + c + 2]) * x2v;
    q3 += to_f(qw[o * 256 + c + 3]) * x3v; k3 += to_f(kw[o * 256 + c + 3]) * x3v;
  }
  qm[((b * 256 + o) << 8) + nw] = (q0 + q1) + (q2 + q3);
  km[((b * 256 + o) << 8) + nw] = (k0 + k1) + (k2 + k3);
}

// ---------------- sim + top-8 via wave shuffles (exact, fewer barriers) -----
__global__ __launch_bounds__(256) void topk_kernel(const float* __restrict__ qm,
                                                   const float* __restrict__ km,
                                                   int* __restrict__ topki)
{
  const int nq = blockIdx.x, b = blockIdx.y, t = threadIdx.x;
  const int lane = t & 63, wid = t >> 6;
  float sim = 0.f;
  for (int c = 0; c < 256; ++c)
    sim += qm[((b * 256 + c) << 8) + nq] * km[((b * 256 + c) << 8) + t];
  __shared__ float vals[256];
  __shared__ float rv4[4];
  __shared__ int ri4[4];
  vals[t] = sim;
  __syncthreads();
  for (int j = 0; j < 8; ++j) {
    float v = vals[t]; int idx = t;
    #pragma unroll
    for (int off = 1; off < 64; off <<= 1) {
      const float v2 = __shfl_xor(v, off);
      const int i2 = __shfl_xor(idx, off);
      if (v2 > v || (v2 == v && i2 < idx)) { v = v2; idx = i2; }
    }
    if (lane == 0) { rv4[wid] = v; ri4[wid] = idx; }
    __syncthreads();
    float bv = rv4[0]; int bi = ri4[0];
    #pragma unroll
    for (int w2 = 1; w2 < 4; ++w2)
      if (rv4[w2] > bv || (rv4[w2] == bv && ri4[w2] < bi)) { bv = rv4[w2]; bi = ri4[w2]; }
    if (t == 0) topki[(b * 256 + nq) * 8 + j] = bi;
    if (t == bi) vals[t] = -3.0e38f;
    __syncthreads();
  }
}

// ---------------- top-k window linear attention: all-MFMA -------------------
__global__ __launch_bounds__(256) void attn_kernel(
    const bf16* __restrict__ qbuf, const bf16* __restrict__ kvT,
    const int* __restrict__ topki, const float* __restrict__ S,
    bf16* __restrict__ msg)
{
  __shared__ bf16 kvB[10240];          // [256 v-rows][40 d] bf16
  __shared__ float ksum_s[256];
  __shared__ float zs2[512];           // [8 h][64 l]
  const int n = blockIdx.x, b = blockIdx.y, t = threadIdx.x;
  const long bpix = (long)b * 16384;
  const int lane = t & 63, wid = t >> 6;
  const int l15 = lane & 15, quad = lane >> 4;
  const int h0 = wid * 2;              // wave owns heads h0, h0+1
  f32x4 kvacc[2][2][2];
  #pragma unroll
  for (int a = 0; a < 2; ++a)
    #pragma unroll
    for (int c = 0; c < 2; ++c)
      #pragma unroll
      for (int d = 0; d < 2; ++d) kvacc[a][c][d] = 0.f;
  int wsel[8];
  #pragma unroll
  for (int j = 0; j < 8; ++j) wsel[j] = topki[(b * 256 + n) * 8 + j];

  const long kvTb = (long)b * 8388608;        // 256 win * 512 ch * 64 px
  #pragma unroll 8
  for (int ck = 0; ck < 16; ++ck) {
    const bf16* base = kvT + kvTb + ((long)wsel[ck >> 1] << 15)
                     + ((ck & 1) * 4 + quad) * 4096;
    #pragma unroll
    for (int hs = 0; hs < 2; ++hs) {
      const int cb = (h0 + hs) * 32;
      const s16x8 a0 = *(const s16x8*)(base + (cb + l15) * 8);
      const s16x8 a1 = *(const s16x8*)(base + (cb + 16 + l15) * 8);
      const s16x8 b0 = *(const s16x8*)(base + (256 + cb + l15) * 8);
      const s16x8 b1 = *(const s16x8*)(base + (256 + cb + 16 + l15) * 8);
      kvacc[hs][0][0] = __builtin_amdgcn_mfma_f32_16x16x32_bf16(a0, b0, kvacc[hs][0][0], 0, 0, 0);
      kvacc[hs][0][1] = __builtin_amdgcn_mfma_f32_16x16x32_bf16(a0, b1, kvacc[hs][0][1], 0, 0, 0);
      kvacc[hs][1][0] = __builtin_amdgcn_mfma_f32_16x16x32_bf16(a1, b0, kvacc[hs][1][0], 0, 0, 0);
      kvacc[hs][1][1] = __builtin_amdgcn_mfma_f32_16x16x32_bf16(a1, b1, kvacc[hs][1][1], 0, 0, 0);
    }
  }

  {
    float ks = 0.f;
    #pragma unroll
    for (int j = 0; j < 8; ++j)
      ks += S[((long)b * 256 + wsel[j]) * 256 + t];
    ksum_s[t] = ks;
  }
  #pragma unroll
  for (int hs = 0; hs < 2; ++hs)
    #pragma unroll
    for (int vt = 0; vt < 2; ++vt) {
      const int row = (h0 + hs) * 32 + vt * 16 + l15;
      #pragma unroll
      for (int dt = 0; dt < 2; ++dt) {
        const f32x4 kv = kvacc[hs][dt][vt];
        uint2 u;
        u.x = (unsigned)(unsigned short)f2s(kv[0])
            | ((unsigned)(unsigned short)f2s(kv[1]) << 16);
        u.y = (unsigned)(unsigned short)f2s(kv[2])
            | ((unsigned)(unsigned short)f2s(kv[3]) << 16);
        *(uint2*)(kvB + row * 40 + dt * 16 + quad * 4) = u;
      }
    }
  __syncthreads();

  const int qh0 = (n >> 4) * 8, qw0 = (n & 15) * 8;
  #pragma unroll
  for (int rep = 0; rep < 2; ++rep) {
    const int idx = t + rep * 256;
    const int l = idx >> 3, hh = idx & 7;
    const long gp = bpix + (qh0 + (l >> 3)) * 128 + qw0 + (l & 7);
    const bf16* qp = qbuf + gp * 256 + hh * 32;
    float dot = 0.f;
    #pragma unroll
    for (int k4 = 0; k4 < 4; ++k4) {
      const s16x8 q8 = *(const s16x8*)(qp + k4 * 8);
      const float4 kA = *(const float4*)(ksum_s + hh * 32 + k4 * 8);
      const float4 kB = *(const float4*)(ksum_s + hh * 32 + k4 * 8 + 4);
      dot += s2f(q8[0]) * kA.x + s2f(q8[1]) * kA.y
           + s2f(q8[2]) * kA.z + s2f(q8[3]) * kA.w
           + s2f(q8[4]) * kB.x + s2f(q8[5]) * kB.y
           + s2f(q8[6]) * kB.z + s2f(q8[7]) * kB.w;
    }
    zs2[hh * 64 + l] = 1.f / (dot + 1e-6f);
  }
  __syncthreads();

  #pragma unroll
  for (int hs = 0; hs < 2; ++hs) {
    const int h = h0 + hs;
    const s16x8 B0 = *(const s16x8*)(kvB + (h * 32 + l15) * 40 + quad * 8);
    const s16x8 B1 = *(const s16x8*)(kvB + (h * 32 + 16 + l15) * 40 + quad * 8);
    #pragma unroll
    for (int i = 0; i < 4; ++i) {
      const int lq = i * 16 + l15;
      const long gpa = bpix + (qh0 + (lq >> 3)) * 128 + qw0 + (lq & 7);
      const s16x8 A = *(const s16x8*)(qbuf + gpa * 256 + h * 32 + quad * 8);
      f32x4 o0 = 0.f, o1 = 0.f;
      o0 = __builtin_amdgcn_mfma_f32_16x16x32_bf16(A, B0, o0, 0, 0, 0);
      o1 = __builtin_amdgcn_mfma_f32_16x16x32_bf16(A, B1, o1, 0, 0, 0);
      const float4 z4 = *(const float4*)(zs2 + h * 64 + i * 16 + quad * 4);
      const float zr[4] = {z4.x, z4.y, z4.z, z4.w};
      #pragma unroll
      for (int r = 0; r < 4; ++r) {
        const int lo = i * 16 + quad * 4 + r;
        const long opix = bpix + (qh0 + (lo >> 3)) * 128 + qw0 + (lo & 7);
        msg[opix * 256 + h * 32 + l15] = __float2bfloat16(o0[r] * zr[r]);
        msg[opix * 256 + h * 32 + 16 + l15] = __float2bfloat16(o1[r] * zr[r]);
      }
    }
  }
}

// ---------------- depthwise 3x3 + bn2 + gelu, strip-mined (8 px/block) ------
__global__ __launch_bounds__(256) void dwconv_kernel(const bf16* __restrict__ y1,
                                                     const bf16* __restrict__ wdw,
                                                     const float* __restrict__ s2,
                                                     const float* __restrict__ t2,
                                                     bf16* __restrict__ y2)
{
  const int strip = blockIdx.x;
  const int bb = strip >> 11;                 // batch (0 when grid=2048)
  const int sl = strip & 2047;
  const int x0 = (sl & 15) * 8;               // strip start col
  const int yy = sl >> 4;                     // row 0..127
  const int m0 = threadIdx.x * 4;             // 4 channels
  const bf16* y1b = y1 + (long)bb * 16777216;
  bf16* y2b = y2 + (long)bb * 16777216;
  float wv[9][4];
  #pragma unroll
  for (int tap = 0; tap < 9; ++tap) {
    const s16x4 w4 = *(const s16x4*)(wdw + tap * 1024 + m0);
    #pragma unroll
    for (int e = 0; e < 4; ++e) wv[tap][e] = s2f(w4[e]);
  }
  float acc[8][4];
  #pragma unroll
  for (int p = 0; p < 8; ++p)
    #pragma unroll
    for (int e = 0; e < 4; ++e) acc[p][e] = 0.f;
  #pragma unroll
  for (int ky = 0; ky < 3; ++ky) {
    const int row = yy + ky - 1;
    if ((unsigned)row < 128u) {
      const bf16* rp = y1b + (long)row * 131072 + m0;
      #pragma unroll
      for (int cr = 0; cr < 10; ++cr) {
        const int xc = x0 + cr - 1;
        if ((unsigned)xc < 128u) {                     // block-uniform
          const s16x4 v4 = *(const s16x4*)(rp + (long)xc * 1024);
          float vf[4];
          #pragma unroll
          for (int e = 0; e < 4; ++e) vf[e] = s2f(v4[e]);
          #pragma unroll
          for (int kx = 0; kx < 3; ++kx) {
            const int p = cr - kx;
            if (p >= 0 && p < 8) {
              #pragma unroll
              for (int e = 0; e < 4; ++e)
                acc[p][e] += wv[ky * 3 + kx][e] * vf[e];
            }
          }
        }
      }
    }
  }
  const float4 sv = *(const float4*)(s2 + m0);
  const float4 tv = *(const float4*)(t2 + m0);
  #pragma unroll
  for (int p = 0; p < 8; ++p) {
    s16x4 o;
    o[0] = f2s(gelu_f(acc[p][0] * sv.x + tv.x));
    o[1] = f2s(gelu_f(acc[p][1] * sv.y + tv.y));
    o[2] = f2s(gelu_f(acc[p][2] * sv.z + tv.z));
    o[3] = f2s(gelu_f(acc[p][3] * sv.w + tv.w));
    *(s16x4*)(y2b + (long)(yy * 128 + x0 + p) * 1024 + m0) = o;
  }
}

// ---------------- per-dtype launch stages ----------------
template <typename TIN>
static void stage_dtype_pre(int want, void* const* d_in, hipStream_t stream,
                            const int* dflag, bf16* wb, float* bnbuf,
                            bf16* xhat_t, float* xmp)
{
  bnprep_kernel<TIN><<<1, 256, 0, stream>>>(dflag, want,
      (const TIN*)d_in[1],  (const TIN*)d_in[2],  (const TIN*)d_in[3],  (const TIN*)d_in[4],
      (const TIN*)d_in[11], (const TIN*)d_in[12], (const TIN*)d_in[13], (const TIN*)d_in[14],
      (const TIN*)d_in[16], (const TIN*)d_in[17], (const TIN*)d_in[18], (const TIN*)d_in[19],
      (const TIN*)d_in[21], (const TIN*)d_in[22], (const TIN*)d_in[23], (const TIN*)d_in[24],
      (const TIN*)d_in[9], bnbuf);
  wconv_kernel<TIN><<<3108, 256, 0, stream>>>(dflag, want,
      (const TIN*)d_in[5], (const TIN*)d_in[6], (const TIN*)d_in[7], (const TIN*)d_in[8],
      (const TIN*)d_in[10], (const TIN*)d_in[20], (const TIN*)d_in[15], wb);
  prenorm_t_kernel<TIN><<<512, 256, 0, stream>>>(dflag, want,
      (const TIN*)d_in[0], bnbuf, xhat_t, xmp);
}

extern "C" void kernel_launch(void* const* d_in, const int* in_sizes, int n_in,
                              void* d_out, int out_size, void* d_ws, size_t ws_size,
                              hipStream_t stream) {
  (void)n_in; (void)out_size;
  // ---- workspace layout (bytes) ----
  // [0        , 16777216 ) xhat_t (prenorm->GEMMs) | xres (merge->end)
  // [16777216 , 17301504 ) Swin (kvgemm epilogue -> attn)
  // [17301504 , 21495808 ) xmp partial window sums (prenorm -> xred)
  // [33554432 , 50331648 ) qbuf elu'd Q (qgemm->attn)
  // [33554432 , 100663296) y1 BOTH batches (W1->dwconv; over dead qbuf/kvT/msg)
  // [50331648 , 83886080 ) kvT fragment-major (kvgemm->attn)
  // [83886080 , 100663296) msg (attn->merge)
  // [100663296, 104857600) wb bf16 | bnbuf | xm | qm | km | topki | dflag
  // [104857600, 171966464) y2 BOTH batches (dwconv->OUT)  [needs ws>=172MB]
  char* W = (char*)d_ws;
  bf16*  xhat_t = (bf16*)(W);
  bf16*  xres   = (bf16*)(W);
  float* Swin   = (float*)(W + 16777216);     // 524288 B
  float* xmp    = (float*)(W + 17301504);     // 4 MB
  bf16*  qbuf   = (bf16*)(W + 33554432);      // 16,777,216 B
  bf16*  kvT    = (bf16*)(W + 50331648);      // 33,554,432 B
  bf16*  msg    = (bf16*)(W + 83886080);
  char*  S      = W + 100663296;
  bf16*  wb     = (bf16*)(S);             // 795648 elems; rows 0..255 qw, 256..767 kv
  bf16*  wmb    = wb + 196608;
  bf16*  w1b    = wb + 262144;
  bf16*  w2b    = wb + 524288;
  bf16*  wdwb   = wb + 786432;
  float* bnbuf  = (float*)(S + 1591296);  // 5376 floats
  float* xm     = (float*)(S + 1612800);
  float* qm     = (float*)(S + 2137088);
  float* km     = (float*)(S + 2661376);
  int*   topki  = (int*)(S + 3185664);
  int*   dflag  = (int*)(S + 3202048);
  const bool big = (ws_size == 0) || (ws_size >= 171966464ull);
  bf16*  y1     = (bf16*)(W + 33554432);      // both batches when big
  bf16*  y2     = big ? (bf16*)(W + 104857600) : (bf16*)(W + 67108864);

  // host-side dtype: x0 is [2][256][128][128] -> 16 MB bf16 / 33.5 MB fp32.
  int known = -1;
  if (in_sizes) {
    if (in_sizes[0] == 16777216) known = 0;
    else if (in_sizes[0] == 33554432) known = 1;
  }

  if (known < 0) detect_kernel<<<1, 64, 0, stream>>>(d_in[0], dflag);

  if (known != 1)
    stage_dtype_pre<bf16>(known == 0 ? -1 : 0, d_in, stream, dflag, wb, bnbuf, xhat_t, xmp);
  if (known != 0)
    stage_dtype_pre<float>(known == 1 ? -1 : 1, d_in, stream, dflag, wb, bnbuf, xhat_t, xmp);

  xred_kernel<<<512, 256, 0, stream>>>(xmp, xm);
  if (known != 1)
    meanproj_kernel<bf16><<<512, 256, 0, stream>>>(dflag, known == 0 ? -1 : 0,
        (const bf16*)d_in[5], (const bf16*)d_in[6], xm, qm, km);
  if (known != 0)
    meanproj_kernel<float><<<512, 256, 0, stream>>>(dflag, known == 1 ? -1 : 1,
        (const float*)d_in[5], (const float*)d_in[6], xm, qm, km);

  // Q GEMM: [32768][256] x qw^T -> qbuf pixel-major, elu'd
  mfma_gemm<0><<<dim3(256, 2), 256, 0, stream>>>(dflag, -1, -1,
      xhat_t, wb, (void*)qbuf, 0, nullptr, nullptr, nullptr, nullptr, 32768, 256, 256);
  // KV GEMM: window-gathered N-tiles -> kvT fragment-major; fused wsum -> Swin
  mfma_gemm<4><<<dim3(256, 4), 256, 0, stream>>>(dflag, -1, -1,
      xhat_t, wb + 65536, (void*)kvT, 0, nullptr, nullptr, nullptr, Swin, 32768, 512, 256);

  topk_kernel<<<dim3(256, 2), 256, 0, stream>>>(qm, km, topki);
  attn_kernel<<<dim3(256, 2), 256, 0, stream>>>(qbuf, kvT, topki, Swin, msg);

  // merge + bias + residual (x0 residual staged through LDS, coalesced)
  if (known != 1)
    mfma_gemm<1, bf16><<<dim3(256, 2), 256, 0, stream>>>(dflag, known == 0 ? -1 : 0, -1,
        msg, wmb, (void*)xres, 0, d_in[0], bnbuf + 5120, nullptr, nullptr, 32768, 256, 256);
  if (known != 0)
    mfma_gemm<1, float><<<dim3(256, 2), 256, 0, stream>>>(dflag, known == 1 ? -1 : 1, -1,
        msg, wmb, (void*)xres, 0, d_in[0], bnbuf + 5120, nullptr, nullptr, 32768, 256, 256);

  if (big) {
    mfma_gemm<2><<<dim3(256, 8), 256, 0, stream>>>(dflag, -1, -1,
        xres, w1b, (void*)y1, 0, nullptr, bnbuf + 512, bnbuf + 1536, nullptr, 32768, 1024, 256);
    dwconv_kernel<<<4096, 256, 0, stream>>>(y1, wdwb, bnbuf + 2560, bnbuf + 3584, y2);
    mfma_gemm<3><<<dim3(256, 2), 256, 0, stream>>>(dflag, -1, known,
        y2, w2b, d_out, 0, xres, bnbuf + 4608, bnbuf + 4864, nullptr, 32768, 256, 1024);
  } else {
    for (int b = 0; b < 2; ++b) {
      bf16* xres_b = xres + (long)b * 4194304;
      mfma_gemm<2><<<dim3(128, 8), 256, 0, stream>>>(dflag, -1, -1,
          xres_b, w1b, (void*)y1, 0, nullptr, bnbuf + 512, bnbuf + 1536, nullptr, 16384, 1024, 256);
      dwconv_kernel<<<2048, 256, 0, stream>>>(y1, wdwb, bnbuf + 2560, bnbuf + 3584, y2);
      mfma_gemm<3><<<dim3(128, 2), 256, 0, stream>>>(dflag, -1, known,
          y2, w2b, d_out, (long)b * 4194304, xres_b,
          bnbuf + 4608, bnbuf + 4864, nullptr, 16384, 256, 1024);
    }
  }
}

// Round 13
// 383.959 us; speedup vs baseline: 1.5424x; 1.5424x over previous
//
#include <hip/hip_runtime.h>
#include <hip/hip_bf16.h>
#include <type_traits>

typedef __hip_bfloat16 bf16;
typedef __attribute__((ext_vector_type(8))) short s16x8;
typedef __attribute__((ext_vector_type(4))) short s16x4;
typedef __attribute__((ext_vector_type(4))) float f32x4;

#define DEVI __device__ __forceinline__

DEVI float bf2f(bf16 x) { return __bfloat162float(x); }
DEVI float to_f(float x) { return x; }
DEVI float to_f(bf16 x) { return __bfloat162float(x); }
// erf via Abramowitz-Stegun 7.1.26 (|err| <= 1.5e-7), branchless.
DEVI float gelu_f(float x) {
  const float y = x * 0.7071067811865476f;
  const float a = fabsf(y);
  const float t = __builtin_amdgcn_rcpf(1.0f + 0.3275911f * a);
  const float p = t * (0.254829592f + t * (-0.284496736f +
                  t * (1.421413741f + t * (-1.453152027f + t * 1.061405429f))));
  const float e = __expf(-a * a);
  const float erfv = copysignf(1.0f - p * e, y);
  return 0.5f * x * (1.0f + erfv);
}
DEVI float elu1(float x) { return x > 0.f ? x + 1.f : __expf(x); }  // elu(x)+1
DEVI float s2f(short s) {
  unsigned u = ((unsigned)(unsigned short)s) << 16;
  float f; __builtin_memcpy(&f, &u, 4); return f;
}
DEVI short f2s(float x) {
  bf16 h = __float2bfloat16(x);
  short s; __builtin_memcpy(&s, &h, 2); return s;
}

// ---------------- dtype detector (fallback when host can't tell) ----------
__global__ void detect_kernel(const void* x0, int* dflag) {
  const int t = threadIdx.x;                  // 64 threads
  const bf16* p = (const bf16*)x0;
  float v = bf2f(p[t * 2]);
  bool ok = (fabsf(v) <= 64.0f);              // false for NaN too
  unsigned long long m = __ballot(ok);
  if (t == 0) dflag[0] = (m == ~0ull) ? 0 : 1;   // 0 = bf16, 1 = fp32
}

// ---------------- bn scale/shift + merge-bias precompute ----------------
// layout: s0[256] t0[256] s1[1024] t1[1024] s2[1024] t2[1024] s3[256] t3[256] mbias[256]
template <typename TIN>
__global__ __launch_bounds__(256) void bnprep_kernel(
    const int* dflag, int want,
    const TIN* g0, const TIN* b0, const TIN* m0, const TIN* v0,
    const TIN* g1, const TIN* b1, const TIN* m1, const TIN* v1,
    const TIN* g2, const TIN* b2, const TIN* m2, const TIN* v2,
    const TIN* g3, const TIN* b3, const TIN* m3, const TIN* v3,
    const TIN* mb, float* out)
{
  if (want >= 0 && dflag[0] != want) return;
  int t = threadIdx.x;
  {
    float s = to_f(g0[t]) / sqrtf(to_f(v0[t]) + 1e-5f);
    out[t] = s; out[256 + t] = to_f(b0[t]) - to_f(m0[t]) * s;
  }
  for (int i = t; i < 1024; i += 256) {
    float s = to_f(g1[i]) / sqrtf(to_f(v1[i]) + 1e-5f);
    out[512 + i] = s; out[1536 + i] = to_f(b1[i]) - to_f(m1[i]) * s;
  }
  for (int i = t; i < 1024; i += 256) {
    float s = to_f(g2[i]) / sqrtf(to_f(v2[i]) + 1e-5f);
    out[2560 + i] = s; out[3584 + i] = to_f(b2[i]) - to_f(m2[i]) * s;
  }
  {
    float s = to_f(g3[t]) / sqrtf(to_f(v3[t]) + 1e-5f);
    out[4608 + t] = s; out[4864 + t] = to_f(b3[t]) - to_f(m3[t]) * s;
    out[5120 + t] = to_f(mb[t]);
  }
}

// ---------------- weight convert to bf16 (concatenated dst) ----------------
template <typename TIN>
__global__ __launch_bounds__(256) void wconv_kernel(
    const int* dflag, int want,
    const TIN* qw, const TIN* kw, const TIN* vw, const TIN* mw,
    const TIN* w1, const TIN* w2, const TIN* dw, bf16* dst)
{
  if (want >= 0 && dflag[0] != want) return;
  int i = blockIdx.x * 256 + threadIdx.x;
  if (i >= 795648) return;
  const TIN* src; int off;
  if (i < 262144) {
    src = (i < 65536) ? qw : (i < 131072) ? kw : (i < 196608) ? vw : mw;
    off = i & 65535;
  } else if (i < 524288) { src = w1; off = i - 262144; }
  else if (i < 786432) { src = w2; off = i - 524288; }
  else {
    src = dw;
    const int o = i - 786432;           // o = tap*1024 + m
    const int tap = o >> 10, m = o & 1023;
    off = m * 9 + tap;                  // src is [m][tap]
    if (o >= 9216) return;
  }
  dst[i] = __float2bfloat16(to_f(src[off]));
}

// ---------------- prenorm + transpose via LDS tiles (gelu only) -------------
// Also emits per-(window,row) partial sums of gelu(bn0 x) into xmp
// [b][wrow][ch][win] (unique slot per thread/cc -> plain stores, no atomics).
template <typename TIN>
__global__ __launch_bounds__(256) void prenorm_t_kernel(
    const int* dflag, int want, const TIN* __restrict__ x0,
    const float* __restrict__ bn, bf16* __restrict__ xhat_t,
    float* __restrict__ xmp)
{
  if (want >= 0 && dflag[0] != want) return;
  __shared__ float T[128][67];
  const int t = threadIdx.x;
  const int tile = blockIdx.x;          // 512 tiles of 64 px
  const int b = tile >> 8;              // 256 tiles per batch
  const int rc = tile & 255;
  const int p0 = rc * 64;               // pixel base within batch
  const int row = rc >> 1, colh = rc & 1;
  const int win = (row >> 3) * 16 + colh * 8 + (t & 7);
  const int wrow = row & 7;
  const long xbase = (long)b * 4194304 + p0;
  const int px_off = (t & 7) * 8;
  const int chr = t >> 3;               // 0..31
  const int ch8 = (t & 15) * 8;
  const int pxw = t >> 4;               // 0..15
  #pragma unroll
  for (int pass = 0; pass < 2; ++pass) {
    const int Hc = pass * 128;
    __syncthreads();                    // prev pass's LDS reads done
    #pragma unroll
    for (int cc = 0; cc < 4; ++cc) {
      const int ch = Hc + chr + 32 * cc;
      const TIN* xp = x0 + (long)ch * 16384 + xbase + px_off;
      float v[8];
      if constexpr (sizeof(TIN) == 2) {
        const s16x8 r = *(const s16x8*)xp;
        #pragma unroll
        for (int j = 0; j < 8; ++j) v[j] = s2f(r[j]);
      } else {
        const float4 a = *(const float4*)xp;
        const float4 c = *(const float4*)(xp + 4);
        v[0] = a.x; v[1] = a.y; v[2] = a.z; v[3] = a.w;
        v[4] = c.x; v[5] = c.y; v[6] = c.z; v[7] = c.w;
      }
      const float s0 = bn[ch], t0 = bn[256 + ch];
      #pragma unroll
      for (int j = 0; j < 8; ++j) v[j] = gelu_f(v[j] * s0 + t0);
      float s8 = v[0];
      #pragma unroll
      for (int j = 1; j < 8; ++j) s8 += v[j];
      xmp[(((b * 8 + wrow) * 256 + ch) << 8) + win] = s8;
      float* Tr = &T[chr + 32 * cc][px_off];
      #pragma unroll
      for (int j = 0; j < 8; ++j) Tr[j] = v[j];
    }
    __syncthreads();
    #pragma unroll
    for (int it = 0; it < 4; ++it) {
      const int px = pxw + 16 * it;
      alignas(16) short o[8];
      #pragma unroll
      for (int j = 0; j < 8; ++j) o[j] = f2s(T[ch8 + j][px]);
      *(uint4*)(xhat_t + (long)(b * 16384 + p0 + px) * 256 + Hc + ch8) =
          *(const uint4*)o;
    }
  }
}

// ---------------- reduce xmp partials -> window means xm [b][c][nw] ---------
__global__ __launch_bounds__(256) void xred_kernel(const float* __restrict__ xmp,
                                                   float* __restrict__ xm)
{
  const int tid = blockIdx.x * 256 + threadIdx.x;   // < 131072
  const int nw = tid & 255, c = (tid >> 8) & 255, b = tid >> 16;
  float s = 0.f;
  #pragma unroll
  for (int w = 0; w < 8; ++w)
    s += xmp[(((b * 8 + w) * 256 + c) << 8) + nw];
  xm[tid] = s * 0.015625f;
}

// ---------------- MFMA GEMM: out[n][m] = epi( sum_k in[n][k] * w[m][k] ) ----
// K-step 32, 2-phase prefetch (round-11 verified config; K-step 64 register
// staging spilled to scratch and regressed 1.5x -- do not re-widen without
// LDS double-buffering).
// MODE 0 PLAIN : out bf16 = elu1(acc) when m0<512 (Q/K pre-activation)
// MODE 1 MERGE : out bf16 = acc + sv[m] + x0[b][m][pix] (LDS-staged residual)
// MODE 2 W1    : out bf16 = gelu(acc*sv[m]+tv[m])
// MODE 3 OUT   : channel-major via LDS transpose; batch-aware; isfp dtype
// MODE 4 KVT   : window-gathered N-tiles -> fragment-major kvT + fused wsum
template <int MODE, typename TRES = bf16>
__global__ __launch_bounds__(256) void mfma_gemm(
    const int* dflag, int want, int isfp,
    const bf16* __restrict__ in, const bf16* __restrict__ w,
    void* __restrict__ out, long obase, const void* __restrict__ resv,
    const float* __restrict__ sv, const float* __restrict__ tv,
    float* __restrict__ aux, int N, int M, int K)
{
  if (want >= 0 && dflag[0] != want) return;
  alignas(16) __shared__ char smem[(MODE == 0 || MODE == 2) ? 20480 : 34816];
  bf16* inT = (bf16*)smem;                   // [128][40]
  bf16* wT  = (bf16*)(smem + 10240);         // [128][40]
  const int t = threadIdx.x;
  const int n0 = blockIdx.x * 128, m0 = blockIdx.y * 128;
  const int sr = t >> 1, sk = (t & 1) * 16;
  const int wid = t >> 6, lane = t & 63;
  const int nw = (wid & 1) * 64, mw = (wid >> 1) * 64;
  const int l15 = lane & 15, quad = lane >> 4;
  f32x4 acc[4][4];
  #pragma unroll
  for (int i = 0; i < 4; ++i)
    #pragma unroll
    for (int j = 0; j < 4; ++j) acc[i][j] = 0.f;
  long inRow;
  if (MODE == 4) {
    const int bb4 = n0 >> 14, w0 = (n0 & 16383) >> 6;
    const int win = w0 + (sr >> 6);
    const int rr = (sr >> 3) & 7, cc = sr & 7;
    inRow = ((long)(bb4 * 16384 + ((win >> 4) * 8 + rr) * 128
                    + (win & 15) * 8 + cc)) * K + sk;
  } else {
    inRow = (long)(n0 + sr) * K + sk;
  }
  const long wRow = (long)(m0 + sr) * K + sk;
  // prologue: tile 0 in flight
  uint4 a0 = *(const uint4*)(in + inRow);
  uint4 a1 = *(const uint4*)(in + inRow + 8);
  uint4 b0 = *(const uint4*)(w + wRow);
  uint4 b1 = *(const uint4*)(w + wRow + 8);
  for (int k0 = 0; k0 < K; k0 += 32) {
    __syncthreads();                         // prev iter's ds_reads done
    *(uint4*)(inT + sr * 40 + sk) = a0;
    *(uint4*)(inT + sr * 40 + sk + 8) = a1;
    *(uint4*)(wT + sr * 40 + sk) = b0;
    *(uint4*)(wT + sr * 40 + sk + 8) = b1;
    __syncthreads();
    if (k0 + 32 < K) {                       // issue NEXT tile before MFMA
      a0 = *(const uint4*)(in + inRow + k0 + 32);
      a1 = *(const uint4*)(in + inRow + k0 + 40);
      b0 = *(const uint4*)(w + wRow + k0 + 32);
      b1 = *(const uint4*)(w + wRow + k0 + 40);
    }
    s16x8 af[4], bfv[4];
    #pragma unroll
    for (int i = 0; i < 4; ++i)
      af[i] = *(const s16x8*)(inT + (nw + i * 16 + l15) * 40 + quad * 8);
    #pragma unroll
    for (int i = 0; i < 4; ++i)
      bfv[i] = *(const s16x8*)(wT + (mw + i * 16 + l15) * 40 + quad * 8);
    #pragma unroll
    for (int i = 0; i < 4; ++i)
      #pragma unroll
      for (int j = 0; j < 4; ++j)
        acc[i][j] = __builtin_amdgcn_mfma_f32_16x16x32_bf16(af[i], bfv[j], acc[i][j], 0, 0, 0);
  }
  if (MODE == 0 || MODE == 2) {
    bf16* ob = (bf16*)out;
    const bool doelu = (MODE == 0) && (m0 < 512);   // Q,K rows pre-activated
    #pragma unroll
    for (int i = 0; i < 4; ++i) {
      #pragma unroll
      for (int r = 0; r < 4; ++r) {
        const int n = n0 + nw + i * 16 + quad * 4 + r;
        #pragma unroll
        for (int j = 0; j < 4; ++j) {
          const int m = m0 + mw + j * 16 + l15;
          float vv = acc[i][j][r];
          if (MODE == 0) { if (doelu) vv = elu1(vv); }
          if (MODE == 2) vv = gelu_f(vv * sv[m] + tv[m]);
          ob[(long)n * M + m] = __float2bfloat16(vv);
        }
      }
    }
  } else if (MODE == 1) {
    // stage x0 residual tile [128 ch][128 px] through LDS (bf16)
    __syncthreads();                         // staging LDS dead
    bf16* xL = (bf16*)smem;                  // [128][132]
    {
      const int bb = n0 >> 14, nloc = n0 & 16383;
      const int chl = t >> 1, pxh = (t & 1) * 64;
      const TRES* xp = (const TRES*)resv + (long)bb * 4194304
                     + (long)(m0 + chl) * 16384 + nloc + pxh;
      alignas(16) short tmp[64];
      if constexpr (std::is_same<TRES, float>::value) {
        #pragma unroll
        for (int q = 0; q < 16; ++q) {
          const float4 f = *(const float4*)(xp + q * 4);
          tmp[q * 4 + 0] = f2s(f.x); tmp[q * 4 + 1] = f2s(f.y);
          tmp[q * 4 + 2] = f2s(f.z); tmp[q * 4 + 3] = f2s(f.w);
        }
      } else {
        #pragma unroll
        for (int q = 0; q < 8; ++q)
          *(s16x8*)(tmp + q * 8) = *(const s16x8*)((const bf16*)xp + q * 8);
      }
      bf16* xd = xL + chl * 132 + pxh;
      #pragma unroll
      for (int q = 0; q < 8; ++q)
        *(uint4*)(xd + q * 8) = *(const uint4*)(tmp + q * 8);
    }
    __syncthreads();
    bf16* ob = (bf16*)out;
    #pragma unroll
    for (int i = 0; i < 4; ++i)
      #pragma unroll
      for (int r = 0; r < 4; ++r) {
        const int nl = nw + i * 16 + quad * 4 + r;
        const int n = n0 + nl;
        #pragma unroll
        for (int j = 0; j < 4; ++j) {
          const int ml = mw + j * 16 + l15;
          const int m = m0 + ml;
          const float vv = acc[i][j][r] + sv[m] + bf2f(xL[ml * 132 + nl]);
          ob[(long)n * 256 + m] = __float2bfloat16(vv);
        }
      }
  } else {
    const int isf = (MODE == 3) ? (isfp >= 0 ? isfp : dflag[0]) : 0;
    __syncthreads();                         // staging LDS now dead
    bf16* T = (bf16*)smem;                   // [128][136]
    #pragma unroll
    for (int i = 0; i < 4; ++i)
      #pragma unroll
      for (int r = 0; r < 4; ++r) {
        const int n = nw + i * 16 + quad * 4 + r;
        #pragma unroll
        for (int j = 0; j < 4; ++j) {
          const int m = mw + j * 16 + l15;
          float vv = acc[i][j][r];
          if (MODE == 3)
            vv = vv * sv[m0 + m] + tv[m0 + m]
               + bf2f(((const bf16*)resv)[(long)(n0 + n) * 256 + m0 + m]);
          else { if (m0 + m < 256) vv = elu1(vv); }
          T[m * 136 + n] = __float2bfloat16(vv);
        }
      }
    __syncthreads();
    const int mr = t >> 1, half = (t & 1) * 64;
    if (MODE == 4) {
      const int bb4 = n0 >> 14, w0 = (n0 & 16383) >> 6;
      const int gm = m0 + mr;
      bf16* bo = (bf16*)out;
      #pragma unroll
      for (int jj = 0; jj < 8; ++jj) {
        const int C = half + jj * 8;
        const int win = w0 + (C >> 6);
        const int pxc = (C & 63) >> 3;
        *(uint4*)(bo + ((long)(bb4 * 256 + win) << 15) + pxc * 4096 + gm * 8) =
            *(const uint4*)(T + mr * 136 + C);
      }
      if (m0 < 256) {                        // fused wsum
        float s = 0.f;
        const bf16* Tr = T + mr * 136 + half;
        #pragma unroll
        for (int c8 = 0; c8 < 8; ++c8) {
          const s16x8 v = *(const s16x8*)(Tr + c8 * 8);
          #pragma unroll
          for (int e = 0; e < 8; ++e) s += s2f(v[e]);
        }
        aux[(long)(bb4 * 256 + w0 + (half >> 6)) * 256 + gm] = s;
      }
    } else {
      // MODE 3: batch-aware channel-major output
      const int bb3 = n0 >> 14, nloc = n0 & 16383;
      if (!isf) {
        bf16* bo = (bf16*)out + obase + (long)bb3 * 4194304;
        #pragma unroll
        for (int jj = 0; jj < 8; ++jj)
          *(uint4*)(bo + (long)(m0 + mr) * 16384 + nloc + half + jj * 8) =
              *(const uint4*)(T + mr * 136 + half + jj * 8);
      } else {
        float* fo = (float*)out + obase + (long)bb3 * 4194304;
        #pragma unroll
        for (int jj = 0; jj < 8; ++jj)
          #pragma unroll
          for (int e = 0; e < 8; ++e)
            fo[(long)(m0 + mr) * 16384 + nloc + half + jj * 8 + e] =
                bf2f(T[mr * 136 + half + jj * 8 + e]);
      }
    }
  }
}

// ---------------- project window means through q_w/k_w (fp32, 4-way ILP) ----
template <typename TIN>
__global__ __launch_bounds__(256) void meanproj_kernel(const int* dflag, int want,
    const TIN* __restrict__ qw, const TIN* __restrict__ kw,
    const float* __restrict__ xm, float* __restrict__ qm, float* __restrict__ km)
{
  if (want >= 0 && dflag[0] != want) return;
  int tid = blockIdx.x * 256 + threadIdx.x;      // < 131072
  int nw = tid & 255, o = (tid >> 8) & 255, b = tid >> 16;
  float q0 = 0.f, q1 = 0.f, q2 = 0.f, q3 = 0.f;
  float k0 = 0.f, k1 = 0.f, k2 = 0.f, k3 = 0.f;
  for (int c = 0; c < 256; c += 4) {
    const float x0v = xm[((b * 256 + c) << 8) + nw];
    const float x1v = xm[((b * 256 + c + 1) << 8) + nw];
    const float x2v = xm[((b * 256 + c + 2) << 8) + nw];
    const float x3v = xm[((b * 256 + c + 3) << 8) + nw];
    q0 += to_f(qw[o * 256 + c]) * x0v;     k0 += to_f(kw[o * 256 + c]) * x0v;
    q1 += to_f(qw[o * 256 + c + 1]) * x1v; k1 += to_f(kw[o * 256 + c + 1]) * x1v;
    q2 += to_f(qw[o * 256 + c + 2]) * x2v; k2 += to_f(kw[o * 256 + c + 2]) * x2v;
    q3 += to_f(qw[o * 256 + c + 3]) * x3v; k3 += to_f(kw[o * 256 + c + 3]) * x3v;
  }
  qm[((b * 256 + o) << 8) + nw] = (q0 + q1) + (q2 + q3);
  km[((b * 256 + o) << 8) + nw] = (k0 + k1) + (k2 + k3);
}

// ---------------- sim + top-8 via wave shuffles (exact, fewer barriers) -----
__global__ __launch_bounds__(256) void topk_kernel(const float* __restrict__ qm,
                                                   const float* __restrict__ km,
                                                   int* __restrict__ topki)
{
  const int nq = blockIdx.x, b = blockIdx.y, t = threadIdx.x;
  const int lane = t & 63, wid = t >> 6;
  float sim = 0.f;
  for (int c = 0; c < 256; ++c)
    sim += qm[((b * 256 + c) << 8) + nq] * km[((b * 256 + c) << 8) + t];
  __shared__ float vals[256];
  __shared__ float rv4[4];
  __shared__ int ri4[4];
  vals[t] = sim;
  __syncthreads();
  for (int j = 0; j < 8; ++j) {
    float v = vals[t]; int idx = t;
    #pragma unroll
    for (int off = 1; off < 64; off <<= 1) {
      const float v2 = __shfl_xor(v, off);
      const int i2 = __shfl_xor(idx, off);
      if (v2 > v || (v2 == v && i2 < idx)) { v = v2; idx = i2; }
    }
    if (lane == 0) { rv4[wid] = v; ri4[wid] = idx; }
    __syncthreads();
    float bv = rv4[0]; int bi = ri4[0];
    #pragma unroll
    for (int w2 = 1; w2 < 4; ++w2)
      if (rv4[w2] > bv || (rv4[w2] == bv && ri4[w2] < bi)) { bv = rv4[w2]; bi = ri4[w2]; }
    if (t == 0) topki[(b * 256 + nq) * 8 + j] = bi;
    if (t == bi) vals[t] = -3.0e38f;
    __syncthreads();
  }
}

// ---------------- top-k window linear attention: all-MFMA -------------------
__global__ __launch_bounds__(256) void attn_kernel(
    const bf16* __restrict__ qbuf, const bf16* __restrict__ kvT,
    const int* __restrict__ topki, const float* __restrict__ S,
    bf16* __restrict__ msg)
{
  __shared__ bf16 kvB[10240];          // [256 v-rows][40 d] bf16
  __shared__ float ksum_s[256];
  __shared__ float zs2[512];           // [8 h][64 l]
  const int n = blockIdx.x, b = blockIdx.y, t = threadIdx.x;
  const long bpix = (long)b * 16384;
  const int lane = t & 63, wid = t >> 6;
  const int l15 = lane & 15, quad = lane >> 4;
  const int h0 = wid * 2;              // wave owns heads h0, h0+1
  f32x4 kvacc[2][2][2];
  #pragma unroll
  for (int a = 0; a < 2; ++a)
    #pragma unroll
    for (int c = 0; c < 2; ++c)
      #pragma unroll
      for (int d = 0; d < 2; ++d) kvacc[a][c][d] = 0.f;
  int wsel[8];
  #pragma unroll
  for (int j = 0; j < 8; ++j) wsel[j] = topki[(b * 256 + n) * 8 + j];

  const long kvTb = (long)b * 8388608;        // 256 win * 512 ch * 64 px
  #pragma unroll 8
  for (int ck = 0; ck < 16; ++ck) {
    const bf16* base = kvT + kvTb + ((long)wsel[ck >> 1] << 15)
                     + ((ck & 1) * 4 + quad) * 4096;
    #pragma unroll
    for (int hs = 0; hs < 2; ++hs) {
      const int cb = (h0 + hs) * 32;
      const s16x8 a0 = *(const s16x8*)(base + (cb + l15) * 8);
      const s16x8 a1 = *(const s16x8*)(base + (cb + 16 + l15) * 8);
      const s16x8 b0 = *(const s16x8*)(base + (256 + cb + l15) * 8);
      const s16x8 b1 = *(const s16x8*)(base + (256 + cb + 16 + l15) * 8);
      kvacc[hs][0][0] = __builtin_amdgcn_mfma_f32_16x16x32_bf16(a0, b0, kvacc[hs][0][0], 0, 0, 0);
      kvacc[hs][0][1] = __builtin_amdgcn_mfma_f32_16x16x32_bf16(a0, b1, kvacc[hs][0][1], 0, 0, 0);
      kvacc[hs][1][0] = __builtin_amdgcn_mfma_f32_16x16x32_bf16(a1, b0, kvacc[hs][1][0], 0, 0, 0);
      kvacc[hs][1][1] = __builtin_amdgcn_mfma_f32_16x16x32_bf16(a1, b1, kvacc[hs][1][1], 0, 0, 0);
    }
  }

  {
    float ks = 0.f;
    #pragma unroll
    for (int j = 0; j < 8; ++j)
      ks += S[((long)b * 256 + wsel[j]) * 256 + t];
    ksum_s[t] = ks;
  }
  #pragma unroll
  for (int hs = 0; hs < 2; ++hs)
    #pragma unroll
    for (int vt = 0; vt < 2; ++vt) {
      const int row = (h0 + hs) * 32 + vt * 16 + l15;
      #pragma unroll
      for (int dt = 0; dt < 2; ++dt) {
        const f32x4 kv = kvacc[hs][dt][vt];
        uint2 u;
        u.x = (unsigned)(unsigned short)f2s(kv[0])
            | ((unsigned)(unsigned short)f2s(kv[1]) << 16);
        u.y = (unsigned)(unsigned short)f2s(kv[2])
            | ((unsigned)(unsigned short)f2s(kv[3]) << 16);
        *(uint2*)(kvB + row * 40 + dt * 16 + quad * 4) = u;
      }
    }
  __syncthreads();

  const int qh0 = (n >> 4) * 8, qw0 = (n & 15) * 8;
  #pragma unroll
  for (int rep = 0; rep < 2; ++rep) {
    const int idx = t + rep * 256;
    const int l = idx >> 3, hh = idx & 7;
    const long gp = bpix + (qh0 + (l >> 3)) * 128 + qw0 + (l & 7);
    const bf16* qp = qbuf + gp * 256 + hh * 32;
    float dot = 0.f;
    #pragma unroll
    for (int k4 = 0; k4 < 4; ++k4) {
      const s16x8 q8 = *(const s16x8*)(qp + k4 * 8);
      const float4 kA = *(const float4*)(ksum_s + hh * 32 + k4 * 8);
      const float4 kB = *(const float4*)(ksum_s + hh * 32 + k4 * 8 + 4);
      dot += s2f(q8[0]) * kA.x + s2f(q8[1]) * kA.y
           + s2f(q8[2]) * kA.z + s2f(q8[3]) * kA.w
           + s2f(q8[4]) * kB.x + s2f(q8[5]) * kB.y
           + s2f(q8[6]) * kB.z + s2f(q8[7]) * kB.w;
    }
    zs2[hh * 64 + l] = 1.f / (dot + 1e-6f);
  }
  __syncthreads();

  #pragma unroll
  for (int hs = 0; hs < 2; ++hs) {
    const int h = h0 + hs;
    const s16x8 B0 = *(const s16x8*)(kvB + (h * 32 + l15) * 40 + quad * 8);
    const s16x8 B1 = *(const s16x8*)(kvB + (h * 32 + 16 + l15) * 40 + quad * 8);
    #pragma unroll
    for (int i = 0; i < 4; ++i) {
      const int lq = i * 16 + l15;
      const long gpa = bpix + (qh0 + (lq >> 3)) * 128 + qw0 + (lq & 7);
      const s16x8 A = *(const s16x8*)(qbuf + gpa * 256 + h * 32 + quad * 8);
      f32x4 o0 = 0.f, o1 = 0.f;
      o0 = __builtin_amdgcn_mfma_f32_16x16x32_bf16(A, B0, o0, 0, 0, 0);
      o1 = __builtin_amdgcn_mfma_f32_16x16x32_bf16(A, B1, o1, 0, 0, 0);
      const float4 z4 = *(const float4*)(zs2 + h * 64 + i * 16 + quad * 4);
      const float zr[4] = {z4.x, z4.y, z4.z, z4.w};
      #pragma unroll
      for (int r = 0; r < 4; ++r) {
        const int lo = i * 16 + quad * 4 + r;
        const long opix = bpix + (qh0 + (lo >> 3)) * 128 + qw0 + (lo & 7);
        msg[opix * 256 + h * 32 + l15] = __float2bfloat16(o0[r] * zr[r]);
        msg[opix * 256 + h * 32 + 16 + l15] = __float2bfloat16(o1[r] * zr[r]);
      }
    }
  }
}

// ---------------- depthwise 3x3 + bn2 + gelu, strip-mined (8 px/block) ------
__global__ __launch_bounds__(256) void dwconv_kernel(const bf16* __restrict__ y1,
                                                     const bf16* __restrict__ wdw,
                                                     const float* __restrict__ s2,
                                                     const float* __restrict__ t2,
                                                     bf16* __restrict__ y2)
{
  const int strip = blockIdx.x;
  const int bb = strip >> 11;                 // batch (0 when grid=2048)
  const int sl = strip & 2047;
  const int x0 = (sl & 15) * 8;               // strip start col
  const int yy = sl >> 4;                     // row 0..127
  const int m0 = threadIdx.x * 4;             // 4 channels
  const bf16* y1b = y1 + (long)bb * 16777216;
  bf16* y2b = y2 + (long)bb * 16777216;
  float wv[9][4];
  #pragma unroll
  for (int tap = 0; tap < 9; ++tap) {
    const s16x4 w4 = *(const s16x4*)(wdw + tap * 1024 + m0);
    #pragma unroll
    for (int e = 0; e < 4; ++e) wv[tap][e] = s2f(w4[e]);
  }
  float acc[8][4];
  #pragma unroll
  for (int p = 0; p < 8; ++p)
    #pragma unroll
    for (int e = 0; e < 4; ++e) acc[p][e] = 0.f;
  #pragma unroll
  for (int ky = 0; ky < 3; ++ky) {
    const int row = yy + ky - 1;
    if ((unsigned)row < 128u) {
      const bf16* rp = y1b + (long)row * 131072 + m0;
      #pragma unroll
      for (int cr = 0; cr < 10; ++cr) {
        const int xc = x0 + cr - 1;
        if ((unsigned)xc < 128u) {                     // block-uniform
          const s16x4 v4 = *(const s16x4*)(rp + (long)xc * 1024);
          float vf[4];
          #pragma unroll
          for (int e = 0; e < 4; ++e) vf[e] = s2f(v4[e]);
          #pragma unroll
          for (int kx = 0; kx < 3; ++kx) {
            const int p = cr - kx;
            if (p >= 0 && p < 8) {
              #pragma unroll
              for (int e = 0; e < 4; ++e)
                acc[p][e] += wv[ky * 3 + kx][e] * vf[e];
            }
          }
        }
      }
    }
  }
  const float4 sv = *(const float4*)(s2 + m0);
  const float4 tv = *(const float4*)(t2 + m0);
  #pragma unroll
  for (int p = 0; p < 8; ++p) {
    s16x4 o;
    o[0] = f2s(gelu_f(acc[p][0] * sv.x + tv.x));
    o[1] = f2s(gelu_f(acc[p][1] * sv.y + tv.y));
    o[2] = f2s(gelu_f(acc[p][2] * sv.z + tv.z));
    o[3] = f2s(gelu_f(acc[p][3] * sv.w + tv.w));
    *(s16x4*)(y2b + (long)(yy * 128 + x0 + p) * 1024 + m0) = o;
  }
}

// ---------------- per-dtype launch stages ----------------
template <typename TIN>
static void stage_dtype_pre(int want, void* const* d_in, hipStream_t stream,
                            const int* dflag, bf16* wb, float* bnbuf,
                            bf16* xhat_t, float* xmp)
{
  bnprep_kernel<TIN><<<1, 256, 0, stream>>>(dflag, want,
      (const TIN*)d_in[1],  (const TIN*)d_in[2],  (const TIN*)d_in[3],  (const TIN*)d_in[4],
      (const TIN*)d_in[11], (const TIN*)d_in[12], (const TIN*)d_in[13], (const TIN*)d_in[14],
      (const TIN*)d_in[16], (const TIN*)d_in[17], (const TIN*)d_in[18], (const TIN*)d_in[19],
      (const TIN*)d_in[21], (const TIN*)d_in[22], (const TIN*)d_in[23], (const TIN*)d_in[24],
      (const TIN*)d_in[9], bnbuf);
  wconv_kernel<TIN><<<3108, 256, 0, stream>>>(dflag, want,
      (const TIN*)d_in[5], (const TIN*)d_in[6], (const TIN*)d_in[7], (const TIN*)d_in[8],
      (const TIN*)d_in[10], (const TIN*)d_in[20], (const TIN*)d_in[15], wb);
  prenorm_t_kernel<TIN><<<512, 256, 0, stream>>>(dflag, want,
      (const TIN*)d_in[0], bnbuf, xhat_t, xmp);
}

extern "C" void kernel_launch(void* const* d_in, const int* in_sizes, int n_in,
                              void* d_out, int out_size, void* d_ws, size_t ws_size,
                              hipStream_t stream) {
  (void)n_in; (void)out_size;
  // ---- workspace layout (bytes) ----
  // [0        , 16777216 ) xhat_t (prenorm->GEMMs) | xres (merge->end)
  // [16777216 , 17301504 ) Swin (kvgemm epilogue -> attn)
  // [17301504 , 21495808 ) xmp partial window sums (prenorm -> xred)
  // [33554432 , 50331648 ) qbuf elu'd Q (qgemm->attn)
  // [33554432 , 100663296) y1 BOTH batches (W1->dwconv; over dead qbuf/kvT/msg)
  // [50331648 , 83886080 ) kvT fragment-major (kvgemm->attn)
  // [83886080 , 100663296) msg (attn->merge)
  // [100663296, 104857600) wb bf16 | bnbuf | xm | qm | km | topki | dflag
  // [104857600, 171966464) y2 BOTH batches (dwconv->OUT)  [needs ws>=172MB]
  char* W = (char*)d_ws;
  bf16*  xhat_t = (bf16*)(W);
  bf16*  xres   = (bf16*)(W);
  float* Swin   = (float*)(W + 16777216);     // 524288 B
  float* xmp    = (float*)(W + 17301504);     // 4 MB
  bf16*  qbuf   = (bf16*)(W + 33554432);      // 16,777,216 B
  bf16*  kvT    = (bf16*)(W + 50331648);      // 33,554,432 B
  bf16*  msg    = (bf16*)(W + 83886080);
  char*  S      = W + 100663296;
  bf16*  wb     = (bf16*)(S);             // 795648 elems; rows 0..255 qw, 256..767 kv
  bf16*  wmb    = wb + 196608;
  bf16*  w1b    = wb + 262144;
  bf16*  w2b    = wb + 524288;
  bf16*  wdwb   = wb + 786432;
  float* bnbuf  = (float*)(S + 1591296);  // 5376 floats
  float* xm     = (float*)(S + 1612800);
  float* qm     = (float*)(S + 2137088);
  float* km     = (float*)(S + 2661376);
  int*   topki  = (int*)(S + 3185664);
  int*   dflag  = (int*)(S + 3202048);
  const bool big = (ws_size == 0) || (ws_size >= 171966464ull);
  bf16*  y1     = (bf16*)(W + 33554432);      // both batches when big
  bf16*  y2     = big ? (bf16*)(W + 104857600) : (bf16*)(W + 67108864);

  // host-side dtype: x0 is [2][256][128][128] -> 16 MB bf16 / 33.5 MB fp32.
  int known = -1;
  if (in_sizes) {
    if (in_sizes[0] == 16777216) known = 0;
    else if (in_sizes[0] == 33554432) known = 1;
  }

  if (known < 0) detect_kernel<<<1, 64, 0, stream>>>(d_in[0], dflag);

  if (known != 1)
    stage_dtype_pre<bf16>(known == 0 ? -1 : 0, d_in, stream, dflag, wb, bnbuf, xhat_t, xmp);
  if (known != 0)
    stage_dtype_pre<float>(known == 1 ? -1 : 1, d_in, stream, dflag, wb, bnbuf, xhat_t, xmp);

  xred_kernel<<<512, 256, 0, stream>>>(xmp, xm);
  if (known != 1)
    meanproj_kernel<bf16><<<512, 256, 0, stream>>>(dflag, known == 0 ? -1 : 0,
        (const bf16*)d_in[5], (const bf16*)d_in[6], xm, qm, km);
  if (known != 0)
    meanproj_kernel<float><<<512, 256, 0, stream>>>(dflag, known == 1 ? -1 : 1,
        (const float*)d_in[5], (const float*)d_in[6], xm, qm, km);

  // Q GEMM: [32768][256] x qw^T -> qbuf pixel-major, elu'd
  mfma_gemm<0><<<dim3(256, 2), 256, 0, stream>>>(dflag, -1, -1,
      xhat_t, wb, (void*)qbuf, 0, nullptr, nullptr, nullptr, nullptr, 32768, 256, 256);
  // KV GEMM: window-gathered N-tiles -> kvT fragment-major; fused wsum -> Swin
  mfma_gemm<4><<<dim3(256, 4), 256, 0, stream>>>(dflag, -1, -1,
      xhat_t, wb + 65536, (void*)kvT, 0, nullptr, nullptr, nullptr, Swin, 32768, 512, 256);

  topk_kernel<<<dim3(256, 2), 256, 0, stream>>>(qm, km, topki);
  attn_kernel<<<dim3(256, 2), 256, 0, stream>>>(qbuf, kvT, topki, Swin, msg);

  // merge + bias + residual (x0 residual staged through LDS, coalesced)
  if (known != 1)
    mfma_gemm<1, bf16><<<dim3(256, 2), 256, 0, stream>>>(dflag, known == 0 ? -1 : 0, -1,
        msg, wmb, (void*)xres, 0, d_in[0], bnbuf + 5120, nullptr, nullptr, 32768, 256, 256);
  if (known != 0)
    mfma_gemm<1, float><<<dim3(256, 2), 256, 0, stream>>>(dflag, known == 1 ? -1 : 1, -1,
        msg, wmb, (void*)xres, 0, d_in[0], bnbuf + 5120, nullptr, nullptr, 32768, 256, 256);

  if (big) {
    mfma_gemm<2><<<dim3(256, 8), 256, 0, stream>>>(dflag, -1, -1,
        xres, w1b, (void*)y1, 0, nullptr, bnbuf + 512, bnbuf + 1536, nullptr, 32768, 1024, 256);
    dwconv_kernel<<<4096, 256, 0, stream>>>(y1, wdwb, bnbuf + 2560, bnbuf + 3584, y2);
    mfma_gemm<3><<<dim3(256, 2), 256, 0, stream>>>(dflag, -1, known,
        y2, w2b, d_out, 0, xres, bnbuf + 4608, bnbuf + 4864, nullptr, 32768, 256, 1024);
  } else {
    for (int b = 0; b < 2; ++b) {
      bf16* xres_b = xres + (long)b * 4194304;
      mfma_gemm<2><<<dim3(128, 8), 256, 0, stream>>>(dflag, -1, -1,
          xres_b, w1b, (void*)y1, 0, nullptr, bnbuf + 512, bnbuf + 1536, nullptr, 16384, 1024, 256);
      dwconv_kernel<<<2048, 256, 0, stream>>>(y1, wdwb, bnbuf + 2560, bnbuf + 3584, y2);
      mfma_gemm<3><<<dim3(128, 2), 256, 0, stream>>>(dflag, -1, known,
          y2, w2b, d_out, (long)b * 4194304, xres_b,
          bnbuf + 4608, bnbuf + 4864, nullptr, 16384, 256, 1024);
    }
  }
}